// Round 12
// baseline (645.123 us; speedup 1.0000x reference)
//
#include <hip/hip_runtime.h>
#include <hip/hip_bf16.h>

typedef __hip_bfloat16 bf16;
typedef __attribute__((ext_vector_type(8))) __bf16 bf16x8;
typedef __attribute__((ext_vector_type(4))) float f32x4;

typedef const __attribute__((address_space(1))) void gvoid;
typedef __attribute__((address_space(3))) void lvoid;

// ---------------------------------------------------------------------------
// gemm256 (R8/R11-verified, 85.5 us): counted-vmcnt ring-pipelined NT GEMM,
// BK=32, 2 blocks/CU, 4 waves x (64M x 128N) per wave (acc 4x8).
// Ring: 3 slots x (A 256x32 + B 128x32) bf16 = 72 KB.
// Pipeline: compute tile t from slot t%3 while t+2's loads fly; vmcnt(6)
// before the barrier drains t+1's 6 loads/thread only. 1 barrier/K-tile.
// LDS swizzle: row-pair XOR (verified 0-conflict R6-R11).
// Plateau note: 800 TF across 4 tile/wave configs; 8-phase recon was slower.
// MODE 0: acc + bias[zh*sBiasZ+m] (v-proj); MODE 3: gamma*acc + xt (PV);
// MODE 1: acc + bias[n] (qk-proj, QKLAY=1).
// ---------------------------------------------------------------------------
template<int MODE, int QKLAY>
__global__ __launch_bounds__(256, 2)
void gemm256(const bf16* __restrict__ A, long lda, long sAb, long sAh,
             const bf16* __restrict__ B, long ldb, long sBb, long sBh,
             void* __restrict__ Cv, long ldc, long sCb, long sCh,
             int K,
             const float* __restrict__ bias, long sBiasZ,
             const float* __restrict__ gamma,
             const bf16* __restrict__ xt, long ldxt)
{
    __shared__ bf16 ring[3][(256 + 128) * 32];   // 73728 B
    const int nt4 = QKLAY ? blockIdx.x : (blockIdx.x >> 3);
    const int zh  = QKLAY ? 0 : (blockIdx.x & 7);
    const int zb  = QKLAY ? 0 : blockIdx.z;
    const bf16* Ab = A + (long)zb * sAb + (long)zh * sAh + (long)blockIdx.y * 256 * lda;
    const bf16* Bb = B + (long)zb * sBb + (long)zh * sBh + (long)nt4 * 128 * ldb;
    const int tid = threadIdx.x;
    const int wave = tid >> 6, lane = tid & 63;
    const int col = lane & 15, quad = lane >> 4;
    const int wm = wave * 64;                    // per-wave 64 rows, full 128 cols

    const bf16* aAddr[4];
    const bf16* bAddr[2];
    int aDst[4], bDst[2];
    #pragma unroll
    for (int i = 0; i < 4; ++i) {
        int cbase = i * 256 + wave * 64;         // wave-uniform chunk base
        int c = cbase + lane;
        int p = c >> 3;
        int sp = (c & 7) ^ (p & 7);
        int m = 2 * p + (sp >> 2);
        int j = sp & 3;
        aAddr[i] = Ab + (long)m * lda + (j << 3);
        aDst[i] = cbase * 8;
    }
    #pragma unroll
    for (int i = 0; i < 2; ++i) {
        int cbase = i * 256 + wave * 64;
        int c = cbase + lane;
        int p = c >> 3;
        int sp = (c & 7) ^ (p & 7);
        int m = 2 * p + (sp >> 2);
        int j = sp & 3;
        bAddr[i] = Bb + (long)m * ldb + (j << 3);
        bDst[i] = 8192 + cbase * 8;
    }

    int offA[4], offB[8];
    #pragma unroll
    for (int mi = 0; mi < 4; ++mi) {
        int m = wm + mi * 16 + col;
        int p = m >> 1;
        int s = (quad | ((m & 1) << 2)) ^ (p & 7);
        offA[mi] = p * 64 + s * 8;
    }
    #pragma unroll
    for (int ni = 0; ni < 8; ++ni) {
        int n = ni * 16 + col;
        int pn = n >> 1;
        int sn = (quad | ((n & 1) << 2)) ^ (pn & 7);
        offB[ni] = 8192 + pn * 64 + sn * 8;
    }

    f32x4 acc[4][8] = {};

    auto STAGE = [&](int rb) {
        bf16* base = &ring[rb][0];
        #pragma unroll
        for (int i = 0; i < 4; ++i) {
            __builtin_amdgcn_global_load_lds((gvoid*)aAddr[i], (lvoid*)(base + aDst[i]), 16, 0, 0);
            aAddr[i] += 32;
        }
        #pragma unroll
        for (int i = 0; i < 2; ++i) {
            __builtin_amdgcn_global_load_lds((gvoid*)bAddr[i], (lvoid*)(base + bDst[i]), 16, 0, 0);
            bAddr[i] += 32;
        }
    };

    const int NT = K >> 5;                        // 32 K-tiles
    STAGE(0);
    STAGE(1);                                     // 12 loads in flight
    asm volatile("s_waitcnt vmcnt(6)" ::: "memory");
    __builtin_amdgcn_s_barrier();
    __builtin_amdgcn_sched_barrier(0);

    int rc = 0;
    for (int t = 0; t < NT; ++t) {
        int r2 = rc + 2; if (r2 >= 3) r2 -= 3;
        if (t + 2 < NT) STAGE(r2);                // issue tile t+2 early
        const bf16* buf = &ring[rc][0];
        bf16x8 af[4], bfr[8];
        #pragma unroll
        for (int mi = 0; mi < 4; ++mi)
            af[mi] = *(const bf16x8*)(buf + offA[mi]);
        #pragma unroll
        for (int ni = 0; ni < 8; ++ni)
            bfr[ni] = *(const bf16x8*)(buf + offB[ni]);
        #pragma unroll
        for (int mi = 0; mi < 4; ++mi)
            #pragma unroll
            for (int ni = 0; ni < 8; ++ni)
                acc[mi][ni] = __builtin_amdgcn_mfma_f32_16x16x32_bf16(
                    af[mi], bfr[ni], acc[mi][ni], 0, 0, 0);
        if (t + 2 < NT)
            asm volatile("s_waitcnt vmcnt(6)" ::: "memory");
        else if (t + 1 < NT)
            asm volatile("s_waitcnt vmcnt(0)" ::: "memory");
        if (t + 1 < NT) {
            __builtin_amdgcn_s_barrier();
            __builtin_amdgcn_sched_barrier(0);
        }
        rc = rc + 1; if (rc >= 3) rc -= 3;
    }

    const long m0 = (long)blockIdx.y * 256 + wm;
    const long n0 = (long)nt4 * 128;
    float g = 0.f;
    if (MODE == 3) g = gamma[zh];
    float bn[8];
    if constexpr (MODE == 1) {
        #pragma unroll
        for (int ni = 0; ni < 8; ++ni)
            bn[ni] = bias[n0 + ni * 16 + col];
    }
    #pragma unroll
    for (int mi = 0; mi < 4; ++mi) {
        #pragma unroll
        for (int ni = 0; ni < 8; ++ni) {
            long mb = m0 + mi * 16 + quad * 4;
            long n  = n0 + ni * 16 + col;
            if constexpr (MODE == 0) {
                bf16* cp = (bf16*)Cv + (long)zb * sCb + (long)zh * sCh + mb * ldc + n;
                const float* bp = bias + zh * sBiasZ + mb;
                #pragma unroll
                for (int r = 0; r < 4; ++r) {
                    *cp = __float2bfloat16(acc[mi][ni][r] + bp[r]);
                    cp += ldc;
                }
            } else if constexpr (MODE == 1) {
                bf16* cp = (bf16*)Cv + mb * ldc + n;
                #pragma unroll
                for (int r = 0; r < 4; ++r) {
                    *cp = __float2bfloat16(acc[mi][ni][r] + bn[ni]);
                    cp += ldc;
                }
            } else {
                bf16* cp = (bf16*)Cv + (long)zb * sCb + (long)zh * sCh + mb * ldc + n;
                const bf16* xp = xt + (long)zb * 1048576 + mb * ldxt + n;
                #pragma unroll
                for (int r = 0; r < 4; ++r) {
                    float xv = __bfloat162float(*xp);
                    *cp = __float2bfloat16(g * acc[mi][ni][r] + xv);
                    cp += ldc;
                    xp += ldxt;
                }
            }
        }
    }
}

// ---------------------------------------------------------------------------
// fc_fused (R12): fc1 + fc2 in one kernel. Per block: 128 rows of ot.
// fc1: y1 = relu(ot . W1^T + b1)   M=128/blk, N=128, K=1024 (gemm_nt loop)
//      -> y1 kept in LDS (XOR-swizzled, verified bank family)
// fc2: out = relu(y1 . W2^T + b2) scattered + xf   K=128, W2 read from global
// LDS: As 16K + Bs 16K + y1 32K = 64 KB -> 2 blocks/CU. Barriers uniform.
// Saves the y1c round-trip (8 MB write + 8 MB read per pass) + 2 launches.
// ---------------------------------------------------------------------------
__global__ __launch_bounds__(256, 2)
void fc_fused(const bf16* __restrict__ ot,
              const bf16* __restrict__ W1b,
              const bf16* __restrict__ W2b,
              const float* __restrict__ b1,
              const float* __restrict__ b2,
              float* __restrict__ outp,
              const float* __restrict__ xf)
{
    __shared__ bf16 As[128 * 64];
    __shared__ bf16 Bs[128 * 64];
    __shared__ bf16 y1[128 * 128];
    const int tid = threadIdx.x;
    const int wave = tid >> 6, lane = tid & 63;
    const int col = lane & 15, quad = lane >> 4;
    const int wm = (wave & 1) * 64, wn = (wave >> 1) * 64;
    const bf16* Ab = ot + (long)blockIdx.y * 128 * 1024;

    // fc1 staging addrs (TBK=64, CPR=8, NSLOT=4) — verified gemm_nt pattern
    const bf16* aAddr[4];
    const bf16* bAddr[4];
    #pragma unroll
    for (int i = 0; i < 4; ++i) {
        int cbase = i * 256 + wave * 64;
        int c = cbase + lane;
        int m = c >> 3, j = c & 7;
        int kch = ((j ^ (m & 7)) << 3);
        aAddr[i] = Ab + (long)m * 1024 + kch;
        bAddr[i] = W1b + (long)m * 1024 + kch;
    }
    int offA[2][4], offB[2][4];
    #pragma unroll
    for (int x = 0; x < 2; ++x) {
        int kq = x * 4 + quad;
        #pragma unroll
        for (int mi = 0; mi < 4; ++mi) {
            int m = wm + mi * 16 + col;
            offA[x][mi] = m * 64 + ((kq ^ (m & 7)) << 3);
            int n = wn + mi * 16 + col;
            offB[x][mi] = n * 64 + ((kq ^ (n & 7)) << 3);
        }
    }

    f32x4 acc[4][4] = {};
    for (int k0 = 0; k0 < 1024; k0 += 64) {
        __syncthreads();
        #pragma unroll
        for (int i = 0; i < 4; ++i) {
            int cbase = i * 256 + wave * 64;
            __builtin_amdgcn_global_load_lds(
                (gvoid*)aAddr[i], (lvoid*)(As + cbase * 8), 16, 0, 0);
            __builtin_amdgcn_global_load_lds(
                (gvoid*)bAddr[i], (lvoid*)(Bs + cbase * 8), 16, 0, 0);
            aAddr[i] += 64;
            bAddr[i] += 64;
        }
        __syncthreads();
        #pragma unroll
        for (int x = 0; x < 2; ++x) {
            bf16x8 af[4], bfr[4];
            #pragma unroll
            for (int mi = 0; mi < 4; ++mi)
                af[mi] = *(const bf16x8*)(As + offA[x][mi]);
            #pragma unroll
            for (int ni = 0; ni < 4; ++ni)
                bfr[ni] = *(const bf16x8*)(Bs + offB[x][ni]);
            #pragma unroll
            for (int mi = 0; mi < 4; ++mi)
                #pragma unroll
                for (int ni = 0; ni < 4; ++ni)
                    acc[mi][ni] = __builtin_amdgcn_mfma_f32_16x16x32_bf16(
                        af[mi], bfr[ni], acc[mi][ni], 0, 0, 0);
        }
    }

    // fc1 epilogue -> y1 LDS (bias + relu), XOR-swizzled:
    // y1[m][n] stored at m*128 + ((n>>3 ^ (m&7))<<3) + (n&7)
    float bn1[4];
    #pragma unroll
    for (int ni = 0; ni < 4; ++ni) bn1[ni] = b1[wn + ni * 16 + col];
    #pragma unroll
    for (int mi = 0; mi < 4; ++mi) {
        #pragma unroll
        for (int ni = 0; ni < 4; ++ni) {
            int mb = wm + mi * 16 + quad * 4;
            int n  = wn + ni * 16 + col;
            int nc = n >> 3, nr = n & 7;
            #pragma unroll
            for (int r = 0; r < 4; ++r) {
                float v = acc[mi][ni][r] + bn1[ni];
                v = v > 0.f ? v : 0.f;
                int m = mb + r;
                y1[m * 128 + (((nc) ^ (m & 7)) << 3) + nr] = __float2bfloat16(v);
            }
        }
    }
    __syncthreads();

    // fc2: C2[m][n2] = sum_k y1[m][k] * W2[n2][k], K=128 (4 x K=32 steps)
    f32x4 acc2[4][4] = {};
    #pragma unroll
    for (int kk = 0; kk < 4; ++kk) {
        int kq = kk * 4 + quad;                   // k-chunk in [0,16)
        bf16x8 af2[4], bf2[4];
        #pragma unroll
        for (int mi = 0; mi < 4; ++mi) {
            int m = wm + mi * 16 + col;
            af2[mi] = *(const bf16x8*)(y1 + m * 128 + ((kq ^ (m & 7)) << 3));
        }
        #pragma unroll
        for (int ni = 0; ni < 4; ++ni) {
            int n = wn + ni * 16 + col;
            bf2[ni] = *(const bf16x8*)(W2b + n * 128 + kq * 8);   // L2-hot 32 KB
        }
        #pragma unroll
        for (int mi = 0; mi < 4; ++mi)
            #pragma unroll
            for (int ni = 0; ni < 4; ++ni)
                acc2[mi][ni] = __builtin_amdgcn_mfma_f32_16x16x32_bf16(
                    af2[mi], bf2[ni], acc2[mi][ni], 0, 0, 0);
    }

    // fc2 epilogue: relu + scatter + residual (MODE-5 logic, verified)
    float bn2[4];
    #pragma unroll
    for (int ni = 0; ni < 4; ++ni) bn2[ni] = b2[wn + ni * 16 + col];
    const long m0 = (long)blockIdx.y * 128 + wm;
    #pragma unroll
    for (int mi = 0; mi < 4; ++mi) {
        #pragma unroll
        for (int ni = 0; ni < 4; ++ni) {
            long mb = m0 + mi * 16 + quad * 4;
            long n  = wn + ni * 16 + col;
            #pragma unroll
            for (int r = 0; r < 4; ++r) {
                long m = mb + r;
                float v = acc2[mi][ni][r] + bn2[ni];
                v = v > 0.f ? v : 0.f;
                long bb = m >> 13, h = (m >> 10) & 7, t = m & 1023;
                long oi = bb * 1048576 + (n * 8 + h) * 1024 + t;
                outp[oi] = v + xf[oi];
            }
        }
    }
}

// Fused energy + softmax. Grid: (slices, T/32). Block 256 (4 waves).
// R11 ring version (verified): 2-slot counted-vmcnt K staging.
__global__ __launch_bounds__(256, 2)
void attn_fused(const bf16* __restrict__ qk, bf16* __restrict__ attn)
{
    constexpr int PAD = 1032;
    __shared__ __align__(16) char smraw[73728];  // Q 8K + ring 2x32K; Sbuf overlays
    __shared__ float red[2][4][32];
    bf16* Qs = (bf16*)smraw;                  // [32][128]
    bf16* Sbuf = (bf16*)smraw;                // [16][PAD] (overlay, post-energy)

    const int z = blockIdx.x;
    const int zb = z >> 3, zh = z & 7;
    const int t0 = blockIdx.y * 32;
    const int tid = threadIdx.x, w = tid >> 6, lane = tid & 63;
    const int col = lane & 15, quad = lane >> 4;

    const bf16* Qbase = qk + ((long)zb * 1024 + t0) * 2048 + zh * 256;
    const bf16* Kbase = qk + (long)zb * 1024 * 2048 + zh * 256 + 128;

    auto stageK = [&](int slot, int si) {
        bf16* Ks = (bf16*)(smraw + 8192 + slot * 32768);
        const bf16* Kb = Kbase + (long)si * 128 * 2048;
        #pragma unroll
        for (int i = 0; i < 8; ++i) {
            int cbase = i * 256 + w * 64;
            int c = cbase + lane;
            int m = c >> 4, j = c & 15;
            __builtin_amdgcn_global_load_lds(
                (gvoid*)(Kb + (long)m * 2048 + ((j ^ (m & 7)) << 3)),
                (lvoid*)(Ks + cbase * 8), 16, 0, 0);
        }
    };

    #pragma unroll
    for (int i = 0; i < 2; ++i) {
        int cbase = i * 256 + w * 64;
        int c = cbase + lane;
        int m = c >> 4, j = c & 15;
        __builtin_amdgcn_global_load_lds(
            (gvoid*)(Qbase + (long)m * 2048 + ((j ^ (m & 7)) << 3)),
            (lvoid*)(Qs + cbase * 8), 16, 0, 0);
    }
    stageK(0, 0);
    stageK(1, 1);
    asm volatile("s_waitcnt vmcnt(8)" ::: "memory");   // Q + tile0 landed
    __builtin_amdgcn_s_barrier();
    __builtin_amdgcn_sched_barrier(0);

    bf16x8 af[2][4];
    #pragma unroll
    for (int mi = 0; mi < 2; ++mi) {
        int m = mi * 16 + col;
        #pragma unroll
        for (int ki = 0; ki < 4; ++ki)
            af[mi][ki] = *(const bf16x8*)(Qs + m * 128 + ((((ki << 2) + quad) ^ (m & 7)) << 3));
    }

    f32x4 acc[2][16] = {};
    #pragma unroll
    for (int si = 0; si < 8; ++si) {
        const bf16* Ks = (const bf16*)(smraw + 8192 + (si & 1) * 32768);
        bf16x8 bfr[2][4];
        #pragma unroll
        for (int ni = 0; ni < 2; ++ni) {
            int n = w * 32 + ni * 16 + col;
            #pragma unroll
            for (int ki = 0; ki < 4; ++ki)
                bfr[ni][ki] = *(const bf16x8*)(Ks + n * 128 + ((((ki << 2) + quad) ^ (n & 7)) << 3));
        }
        asm volatile("s_waitcnt lgkmcnt(0)" ::: "memory");
        __builtin_amdgcn_sched_barrier(0);
        #pragma unroll
        for (int ki = 0; ki < 4; ++ki)
            #pragma unroll
            for (int mi = 0; mi < 2; ++mi)
                #pragma unroll
                for (int ni = 0; ni < 2; ++ni)
                    acc[mi][si * 2 + ni] = __builtin_amdgcn_mfma_f32_16x16x32_bf16(
                        af[mi][ki], bfr[ni][ki], acc[mi][si * 2 + ni], 0, 0, 0);
        __builtin_amdgcn_s_barrier();              // all waves done reading slot
        if (si + 2 < 8) {
            stageK(si & 1, si + 2);
            asm volatile("s_waitcnt vmcnt(8)" ::: "memory");   // tile si+1 landed
        } else {
            asm volatile("s_waitcnt vmcnt(0)" ::: "memory");
        }
        __builtin_amdgcn_s_barrier();
        __builtin_amdgcn_sched_barrier(0);
    }

    float rmx[2][4], rinv[2][4];
    #pragma unroll
    for (int mi = 0; mi < 2; ++mi)
        #pragma unroll
        for (int r = 0; r < 4; ++r) {
            float mx = acc[mi][0][r];
            #pragma unroll
            for (int j = 1; j < 16; ++j) mx = fmaxf(mx, acc[mi][j][r]);
            #pragma unroll
            for (int off = 1; off < 16; off <<= 1) mx = fmaxf(mx, __shfl_xor(mx, off, 64));
            rmx[mi][r] = mx;
        }
    if (col == 0) {
        #pragma unroll
        for (int mi = 0; mi < 2; ++mi)
            #pragma unroll
            for (int r = 0; r < 4; ++r)
                red[0][w][mi * 16 + quad * 4 + r] = rmx[mi][r];
    }
    __syncthreads();
    #pragma unroll
    for (int mi = 0; mi < 2; ++mi)
        #pragma unroll
        for (int r = 0; r < 4; ++r) {
            int row = mi * 16 + quad * 4 + r;
            rmx[mi][r] = fmaxf(fmaxf(red[0][0][row], red[0][1][row]),
                               fmaxf(red[0][2][row], red[0][3][row]));
        }
    #pragma unroll
    for (int mi = 0; mi < 2; ++mi)
        #pragma unroll
        for (int r = 0; r < 4; ++r) {
            float s = 0.f;
            #pragma unroll
            for (int j = 0; j < 16; ++j) {
                acc[mi][j][r] = __expf(acc[mi][j][r] - rmx[mi][r]);
                s += acc[mi][j][r];
            }
            #pragma unroll
            for (int off = 1; off < 16; off <<= 1) s += __shfl_xor(s, off, 64);
            rinv[mi][r] = s;
        }
    if (col == 0) {
        #pragma unroll
        for (int mi = 0; mi < 2; ++mi)
            #pragma unroll
            for (int r = 0; r < 4; ++r)
                red[1][w][mi * 16 + quad * 4 + r] = rinv[mi][r];
    }
    __syncthreads();
    #pragma unroll
    for (int mi = 0; mi < 2; ++mi)
        #pragma unroll
        for (int r = 0; r < 4; ++r) {
            int row = mi * 16 + quad * 4 + r;
            float s4 = red[1][0][row] + red[1][1][row] + red[1][2][row] + red[1][3][row];
            rinv[mi][r] = 1.0f / s4;
        }

    bf16* dst = attn + ((long)(zb * 8 + zh)) * 1048576 + (long)t0 * 1024;
    #pragma unroll
    for (int mi = 0; mi < 2; ++mi) {
        __syncthreads();
        #pragma unroll
        for (int j = 0; j < 16; ++j) {
            int colb = (j >> 1) * 128 + w * 32 + (j & 1) * 16 + col;
            #pragma unroll
            for (int r = 0; r < 4; ++r) {
                int rowh = quad * 4 + r;
                Sbuf[rowh * PAD + colb] = __float2bfloat16(acc[mi][j][r] * rinv[mi][r]);
            }
        }
        __syncthreads();
        #pragma unroll
        for (int i = 0; i < 8; ++i) {
            int c = i * 256 + tid;             // 16 rows x 128 chunks
            int rowh = c >> 7, jj = c & 127;
            bf16x8 vv = *(const bf16x8*)(Sbuf + rowh * PAD + jj * 8);
            *(bf16x8*)(dst + (long)(mi * 16 + rowh) * 1024 + jj * 8) = vv;
        }
    }
}

// x (B,C,T) f32 -> xt (B,T,C) bf16, 32x32 LDS tiles
__global__ __launch_bounds__(256)
void transpose_cast_x(const float* __restrict__ x, bf16* __restrict__ xt)
{
    __shared__ float tile[32][33];
    int b = blockIdx.z;
    int c0 = blockIdx.y * 32, t0 = blockIdx.x * 32;
    int tx = threadIdx.x & 31, ty = threadIdx.x >> 5;  // ty 0..7
    const float* xb = x + (long)b * 1024 * 1024;
    #pragma unroll
    for (int i = 0; i < 4; ++i) {
        int c = ty + i * 8;
        tile[c][tx] = xb[(long)(c0 + c) * 1024 + t0 + tx];
    }
    __syncthreads();
    bf16* xtb = xt + (long)b * 1024 * 1024;
    #pragma unroll
    for (int i = 0; i < 4; ++i) {
        int t = ty + i * 8;
        xtb[(long)(t0 + t) * 1024 + c0 + tx] = __float2bfloat16(tile[tx][t]);
    }
}

__global__ __launch_bounds__(256)
void cast_f2b(const float* __restrict__ in, bf16* __restrict__ out, long n)
{
    long i = (long)blockIdx.x * 256 + threadIdx.x;
    long stride = (long)gridDim.x * 256;
    for (; i < n; i += stride) out[i] = __float2bfloat16(in[i]);
}

// Build stacked qk weight (2048 x 1024 bf16)
__global__ __launch_bounds__(256)
void build_wqk(const float* __restrict__ Wq, const float* __restrict__ Wk,
               const float* __restrict__ bq, const float* __restrict__ bk,
               bf16* __restrict__ Wqk, float* __restrict__ biasqk)
{
    long i = (long)blockIdx.x * 256 + threadIdx.x;   // 2048*1024 total
    long r = i >> 10, c = i & 1023;
    long h = r >> 8, rr = r & 255;
    float v = (rr < 128) ? Wq[(h * 128 + rr) * 1024 + c]
                         : Wk[(h * 128 + (rr - 128)) * 1024 + c];
    Wqk[i] = __float2bfloat16(v);
    if (c == 0)
        biasqk[r] = (rr < 128) ? bq[h * 128 + rr] : bk[h * 128 + rr - 128];
}

extern "C" void kernel_launch(void* const* d_in, const int* in_sizes, int n_in,
                              void* d_out, int out_size, void* d_ws, size_t ws_size,
                              hipStream_t stream)
{
    const float* x     = (const float*)d_in[0];
    const float* Wq    = (const float*)d_in[1];
    const float* bq    = (const float*)d_in[2];
    const float* Wk    = (const float*)d_in[3];
    const float* bk    = (const float*)d_in[4];
    const float* Wv    = (const float*)d_in[5];
    const float* bv    = (const float*)d_in[6];
    const float* gamma = (const float*)d_in[7];
    const float* W1    = (const float*)d_in[8];
    const float* b1    = (const float*)d_in[9];
    const float* W2    = (const float*)d_in[10];
    const float* b2    = (const float*)d_in[11];
    float* out = (float*)d_out;

    char* base = (char*)d_ws;
    const long MB = 1048576;
    bf16*  xt   = (bf16*)(base);
    bf16*  Wvb  = (bf16*)(base + 16 * MB);
    bf16*  vbuf = (bf16*)(base + 32 * MB);
    bf16*  Wqk  = (bf16*)(base + 32 * MB);          // dead after qk-proj
    float* bqk  = (float*)(base + 36 * MB);         // dead after qk-proj
    bf16*  attb = (bf16*)(base + 96 * MB);
    bf16*  W1b  = (bf16*)(base + 96 * MB);          // post-O overlay, re-cast per pass
    bf16*  W2b  = (bf16*)(base + 96 * MB + 524288);
    bf16*  ot   = (bf16*)(base + 160 * MB);
    bf16*  qkt  = (bf16*)(base + 224 * MB);

    dim3 blk(256);
    transpose_cast_x<<<dim3(32, 32, 8), blk, 0, stream>>>(x, xt);
    build_wqk<<<8192, blk, 0, stream>>>(Wq, Wk, bq, bk, Wqk, bqk);
    cast_f2b<<<4096, blk, 0, stream>>>(Wv, Wvb, 8192ll * 1024);

    const long M1 = 1048576, M2 = 2097152, M8 = 8388608;

    // qk_t: M=8192 (b,t), N=2048 (h*256+o), K=1024 — gemm256 QKLAY (512 blocks)
    gemm256<1, 1><<<dim3(16, 32, 1), blk, 0, stream>>>(
        xt, 1024, 0, 0, Wqk, 1024, 0, 0, qkt, 2048, 0, 0, 1024,
        bqk, 0, nullptr, nullptr, 0);

    for (int q = 0; q < 2; ++q) {
        const long b0 = (long)q * 4;
        const bf16* xtq = xt + b0 * M1;
        // v(zb,zh;c,s) = Wv[zh](c,ci) . xt(b0+zb;s,ci)^T + bv[zh,c]
        gemm256<0, 0><<<dim3(64, 4, 4), blk, 0, stream>>>(
            Wvb, 1024, 0, M1, xtq, 1024, M1, 0, vbuf, 1024, M8, M1, 1024,
            bv, 1024, nullptr, nullptr, 0);
        // fused E + softmax -> attb bf16 (1024 blocks)
        attn_fused<<<dim3(32, 32, 1), blk, 0, stream>>>(
            qkt + b0 * M2, attb);
        // heads_t(zb,zh;t,c) = gamma[zh]*(attn(t,s).v(c,s)^T) + xt(b0+zb;t,c)
        gemm256<3, 0><<<dim3(64, 4, 4), blk, 0, stream>>>(
            attb, 1024, M8, M1, vbuf, 1024, M8, M1,
            ot, 1024, M8, M1, 1024,
            nullptr, 0, gamma, xtq, 1024);
        // attb dead: cast FC weights into its region (re-done each pass)
        cast_f2b<<<512, blk, 0, stream>>>(W1, W1b, 128 * 1024);
        cast_f2b<<<64, blk, 0, stream>>>(W2, W2b, 128 * 128);
        // fc1+fc2 fused: M=32768 rows, 256 blocks of 128 rows
        fc_fused<<<dim3(1, 256, 1), blk, 0, stream>>>(
            ot, W1b, W2b, b1, b2, out + b0 * M1, x + b0 * M1);
    }
}

// Round 13
// 643.343 us; speedup vs baseline: 1.0028x; 1.0028x over previous
//
#include <hip/hip_runtime.h>
#include <hip/hip_bf16.h>

typedef __hip_bfloat16 bf16;
typedef __attribute__((ext_vector_type(8))) __bf16 bf16x8;
typedef __attribute__((ext_vector_type(4))) float f32x4;

typedef const __attribute__((address_space(1))) void gvoid;
typedef __attribute__((address_space(3))) void lvoid;

// ---------------------------------------------------------------------------
// gemm256 (R8/R11-verified, 85.5 us): counted-vmcnt ring-pipelined NT GEMM,
// BK=32, 2 blocks/CU, 4 waves x (64M x 128N) per wave (acc 4x8).
// Ring: 3 slots x (A 256x32 + B 128x32) bf16 = 72 KB.
// Pipeline: compute tile t from slot t%3 while t+2's loads fly; vmcnt(6)
// before the barrier drains t+1's 6 loads/thread only. 1 barrier/K-tile.
// LDS swizzle: row-pair XOR (verified 0-conflict R6-R12).
// Plateau note: 800 TF across 4 tile/wave configs; 8-phase recon was slower.
// MODE 0: acc + bias[zh*sBiasZ+m] (v-proj); MODE 3: gamma*acc + xt (PV);
// MODE 1: acc + bias[n] (qk-proj, QKLAY=1).
// ---------------------------------------------------------------------------
template<int MODE, int QKLAY>
__global__ __launch_bounds__(256, 2)
void gemm256(const bf16* __restrict__ A, long lda, long sAb, long sAh,
             const bf16* __restrict__ B, long ldb, long sBb, long sBh,
             void* __restrict__ Cv, long ldc, long sCb, long sCh,
             int K,
             const float* __restrict__ bias, long sBiasZ,
             const float* __restrict__ gamma,
             const bf16* __restrict__ xt, long ldxt)
{
    __shared__ bf16 ring[3][(256 + 128) * 32];   // 73728 B
    const int nt4 = QKLAY ? blockIdx.x : (blockIdx.x >> 3);
    const int zh  = QKLAY ? 0 : (blockIdx.x & 7);
    const int zb  = QKLAY ? 0 : blockIdx.z;
    const bf16* Ab = A + (long)zb * sAb + (long)zh * sAh + (long)blockIdx.y * 256 * lda;
    const bf16* Bb = B + (long)zb * sBb + (long)zh * sBh + (long)nt4 * 128 * ldb;
    const int tid = threadIdx.x;
    const int wave = tid >> 6, lane = tid & 63;
    const int col = lane & 15, quad = lane >> 4;
    const int wm = wave * 64;                    // per-wave 64 rows, full 128 cols

    const bf16* aAddr[4];
    const bf16* bAddr[2];
    int aDst[4], bDst[2];
    #pragma unroll
    for (int i = 0; i < 4; ++i) {
        int cbase = i * 256 + wave * 64;         // wave-uniform chunk base
        int c = cbase + lane;
        int p = c >> 3;
        int sp = (c & 7) ^ (p & 7);
        int m = 2 * p + (sp >> 2);
        int j = sp & 3;
        aAddr[i] = Ab + (long)m * lda + (j << 3);
        aDst[i] = cbase * 8;
    }
    #pragma unroll
    for (int i = 0; i < 2; ++i) {
        int cbase = i * 256 + wave * 64;
        int c = cbase + lane;
        int p = c >> 3;
        int sp = (c & 7) ^ (p & 7);
        int m = 2 * p + (sp >> 2);
        int j = sp & 3;
        bAddr[i] = Bb + (long)m * ldb + (j << 3);
        bDst[i] = 8192 + cbase * 8;
    }

    int offA[4], offB[8];
    #pragma unroll
    for (int mi = 0; mi < 4; ++mi) {
        int m = wm + mi * 16 + col;
        int p = m >> 1;
        int s = (quad | ((m & 1) << 2)) ^ (p & 7);
        offA[mi] = p * 64 + s * 8;
    }
    #pragma unroll
    for (int ni = 0; ni < 8; ++ni) {
        int n = ni * 16 + col;
        int pn = n >> 1;
        int sn = (quad | ((n & 1) << 2)) ^ (pn & 7);
        offB[ni] = 8192 + pn * 64 + sn * 8;
    }

    f32x4 acc[4][8] = {};

    auto STAGE = [&](int rb) {
        bf16* base = &ring[rb][0];
        #pragma unroll
        for (int i = 0; i < 4; ++i) {
            __builtin_amdgcn_global_load_lds((gvoid*)aAddr[i], (lvoid*)(base + aDst[i]), 16, 0, 0);
            aAddr[i] += 32;
        }
        #pragma unroll
        for (int i = 0; i < 2; ++i) {
            __builtin_amdgcn_global_load_lds((gvoid*)bAddr[i], (lvoid*)(base + bDst[i]), 16, 0, 0);
            bAddr[i] += 32;
        }
    };

    const int NT = K >> 5;                        // 32 K-tiles
    STAGE(0);
    STAGE(1);                                     // 12 loads in flight
    asm volatile("s_waitcnt vmcnt(6)" ::: "memory");
    __builtin_amdgcn_s_barrier();
    __builtin_amdgcn_sched_barrier(0);

    int rc = 0;
    for (int t = 0; t < NT; ++t) {
        int r2 = rc + 2; if (r2 >= 3) r2 -= 3;
        if (t + 2 < NT) STAGE(r2);                // issue tile t+2 early
        const bf16* buf = &ring[rc][0];
        bf16x8 af[4], bfr[8];
        #pragma unroll
        for (int mi = 0; mi < 4; ++mi)
            af[mi] = *(const bf16x8*)(buf + offA[mi]);
        #pragma unroll
        for (int ni = 0; ni < 8; ++ni)
            bfr[ni] = *(const bf16x8*)(buf + offB[ni]);
        #pragma unroll
        for (int mi = 0; mi < 4; ++mi)
            #pragma unroll
            for (int ni = 0; ni < 8; ++ni)
                acc[mi][ni] = __builtin_amdgcn_mfma_f32_16x16x32_bf16(
                    af[mi], bfr[ni], acc[mi][ni], 0, 0, 0);
        if (t + 2 < NT)
            asm volatile("s_waitcnt vmcnt(6)" ::: "memory");
        else if (t + 1 < NT)
            asm volatile("s_waitcnt vmcnt(0)" ::: "memory");
        if (t + 1 < NT) {
            __builtin_amdgcn_s_barrier();
            __builtin_amdgcn_sched_barrier(0);
        }
        rc = rc + 1; if (rc >= 3) rc -= 3;
    }

    const long m0 = (long)blockIdx.y * 256 + wm;
    const long n0 = (long)nt4 * 128;
    float g = 0.f;
    if (MODE == 3) g = gamma[zh];
    float bn[8];
    if constexpr (MODE == 1) {
        #pragma unroll
        for (int ni = 0; ni < 8; ++ni)
            bn[ni] = bias[n0 + ni * 16 + col];
    }
    #pragma unroll
    for (int mi = 0; mi < 4; ++mi) {
        #pragma unroll
        for (int ni = 0; ni < 8; ++ni) {
            long mb = m0 + mi * 16 + quad * 4;
            long n  = n0 + ni * 16 + col;
            if constexpr (MODE == 0) {
                bf16* cp = (bf16*)Cv + (long)zb * sCb + (long)zh * sCh + mb * ldc + n;
                const float* bp = bias + zh * sBiasZ + mb;
                #pragma unroll
                for (int r = 0; r < 4; ++r) {
                    *cp = __float2bfloat16(acc[mi][ni][r] + bp[r]);
                    cp += ldc;
                }
            } else if constexpr (MODE == 1) {
                bf16* cp = (bf16*)Cv + mb * ldc + n;
                #pragma unroll
                for (int r = 0; r < 4; ++r) {
                    *cp = __float2bfloat16(acc[mi][ni][r] + bn[ni]);
                    cp += ldc;
                }
            } else {
                bf16* cp = (bf16*)Cv + (long)zb * sCb + (long)zh * sCh + mb * ldc + n;
                const bf16* xp = xt + (long)zb * 1048576 + mb * ldxt + n;
                #pragma unroll
                for (int r = 0; r < 4; ++r) {
                    float xv = __bfloat162float(*xp);
                    *cp = __float2bfloat16(g * acc[mi][ni][r] + xv);
                    cp += ldc;
                    xp += ldxt;
                }
            }
        }
    }
}

// ---------------------------------------------------------------------------
// fc_fused v2 (R13): fc1 + fc2 in one kernel, fc1 K-loop ring-pipelined.
// Per block: 128 rows of ot.
// fc1: y1 = relu(ot . W1^T + b1)  M=128, N=128, K=1024 via 3-slot counted-
//      vmcnt ring (gemm256 pattern; slot = A 128x32 + B 128x32 = 16 KB;
//      4 loads/thread/tile -> vmcnt(4) cadence). y1 -> LDS XOR-swizzled.
// fc2: out = relu(y1 . W2^T + b2) scattered + xf  K=128, W2 L2-hot global.
// LDS: ring 48 KB + y1 32 KB = 80 KB -> 2 blocks/CU (was 1). Barriers uniform.
// ---------------------------------------------------------------------------
__global__ __launch_bounds__(256, 2)
void fc_fused(const bf16* __restrict__ ot,
              const bf16* __restrict__ W1b,
              const bf16* __restrict__ W2b,
              const float* __restrict__ b1,
              const float* __restrict__ b2,
              float* __restrict__ outp,
              const float* __restrict__ xf)
{
    __shared__ bf16 ring[3][128 * 32 * 2];       // A (4096 el) + B (4096 el) per slot
    __shared__ bf16 y1[128 * 128];               // 32 KB
    const int tid = threadIdx.x;
    const int wave = tid >> 6, lane = tid & 63;
    const int col = lane & 15, quad = lane >> 4;
    const int wm = (wave & 1) * 64, wn = (wave >> 1) * 64;
    const bf16* Ab = ot + (long)blockIdx.y * 128 * 1024;

    // staging: A 512 chunks (2/thread), B 512 chunks (2/thread); row-pair XOR
    const bf16* aAddr[2];
    const bf16* bAddr[2];
    int aDst[2], bDst[2];
    #pragma unroll
    for (int i = 0; i < 2; ++i) {
        int cbase = i * 256 + wave * 64;
        int c = cbase + lane;
        int p = c >> 3;
        int sp = (c & 7) ^ (p & 7);
        int m = 2 * p + (sp >> 2);
        int j = sp & 3;
        aAddr[i] = Ab + (long)m * 1024 + (j << 3);
        aDst[i] = cbase * 8;
        bAddr[i] = W1b + (long)m * 1024 + (j << 3);
        bDst[i] = 4096 + cbase * 8;
    }

    // K-invariant read offsets within a slot (kq = quad)
    int offA[4], offB[4];
    #pragma unroll
    for (int mi = 0; mi < 4; ++mi) {
        int m = wm + mi * 16 + col;
        int p = m >> 1;
        int s = (quad | ((m & 1) << 2)) ^ (p & 7);
        offA[mi] = p * 64 + s * 8;
        int n = wn + mi * 16 + col;
        int pn = n >> 1;
        int sn = (quad | ((n & 1) << 2)) ^ (pn & 7);
        offB[mi] = 4096 + pn * 64 + sn * 8;
    }

    auto STAGE = [&](int rb) {
        bf16* base = &ring[rb][0];
        #pragma unroll
        for (int i = 0; i < 2; ++i) {
            __builtin_amdgcn_global_load_lds((gvoid*)aAddr[i], (lvoid*)(base + aDst[i]), 16, 0, 0);
            aAddr[i] += 32;
        }
        #pragma unroll
        for (int i = 0; i < 2; ++i) {
            __builtin_amdgcn_global_load_lds((gvoid*)bAddr[i], (lvoid*)(base + bDst[i]), 16, 0, 0);
            bAddr[i] += 32;
        }
    };

    f32x4 acc[4][4] = {};
    const int NT = 32;                            // K=1024, BK=32
    STAGE(0);
    STAGE(1);                                     // 8 loads in flight
    asm volatile("s_waitcnt vmcnt(4)" ::: "memory");   // tile0 landed, tile1 flying
    __builtin_amdgcn_s_barrier();
    __builtin_amdgcn_sched_barrier(0);

    int rc = 0;
    for (int t = 0; t < NT; ++t) {
        int r2 = rc + 2; if (r2 >= 3) r2 -= 3;
        if (t + 2 < NT) STAGE(r2);
        const bf16* buf = &ring[rc][0];
        bf16x8 af[4], bfr[4];
        #pragma unroll
        for (int mi = 0; mi < 4; ++mi)
            af[mi] = *(const bf16x8*)(buf + offA[mi]);
        #pragma unroll
        for (int ni = 0; ni < 4; ++ni)
            bfr[ni] = *(const bf16x8*)(buf + offB[ni]);
        #pragma unroll
        for (int mi = 0; mi < 4; ++mi)
            #pragma unroll
            for (int ni = 0; ni < 4; ++ni)
                acc[mi][ni] = __builtin_amdgcn_mfma_f32_16x16x32_bf16(
                    af[mi], bfr[ni], acc[mi][ni], 0, 0, 0);
        if (t + 2 < NT)
            asm volatile("s_waitcnt vmcnt(4)" ::: "memory");
        else if (t + 1 < NT)
            asm volatile("s_waitcnt vmcnt(0)" ::: "memory");
        if (t + 1 < NT) {
            __builtin_amdgcn_s_barrier();
            __builtin_amdgcn_sched_barrier(0);
        }
        rc = rc + 1; if (rc >= 3) rc -= 3;
    }

    // fc1 epilogue -> y1 LDS (bias + relu), XOR-swizzled:
    // y1[m][n] stored at m*128 + ((n>>3 ^ (m&7))<<3) + (n&7)
    float bn1[4];
    #pragma unroll
    for (int ni = 0; ni < 4; ++ni) bn1[ni] = b1[wn + ni * 16 + col];
    #pragma unroll
    for (int mi = 0; mi < 4; ++mi) {
        #pragma unroll
        for (int ni = 0; ni < 4; ++ni) {
            int mb = wm + mi * 16 + quad * 4;
            int n  = wn + ni * 16 + col;
            int nc = n >> 3, nr = n & 7;
            #pragma unroll
            for (int r = 0; r < 4; ++r) {
                float v = acc[mi][ni][r] + bn1[ni];
                v = v > 0.f ? v : 0.f;
                int m = mb + r;
                y1[m * 128 + (((nc) ^ (m & 7)) << 3) + nr] = __float2bfloat16(v);
            }
        }
    }
    __syncthreads();

    // fc2: C2[m][n2] = sum_k y1[m][k] * W2[n2][k], K=128 (4 x K=32 steps)
    f32x4 acc2[4][4] = {};
    #pragma unroll
    for (int kk = 0; kk < 4; ++kk) {
        int kq = kk * 4 + quad;                   // k-chunk in [0,16)
        bf16x8 af2[4], bf2[4];
        #pragma unroll
        for (int mi = 0; mi < 4; ++mi) {
            int m = wm + mi * 16 + col;
            af2[mi] = *(const bf16x8*)(y1 + m * 128 + ((kq ^ (m & 7)) << 3));
        }
        #pragma unroll
        for (int ni = 0; ni < 4; ++ni) {
            int n = wn + ni * 16 + col;
            bf2[ni] = *(const bf16x8*)(W2b + n * 128 + kq * 8);   // L2-hot 32 KB
        }
        #pragma unroll
        for (int mi = 0; mi < 4; ++mi)
            #pragma unroll
            for (int ni = 0; ni < 4; ++ni)
                acc2[mi][ni] = __builtin_amdgcn_mfma_f32_16x16x32_bf16(
                    af2[mi], bf2[ni], acc2[mi][ni], 0, 0, 0);
    }

    // fc2 epilogue: relu + scatter + residual (MODE-5 logic, verified)
    float bn2[4];
    #pragma unroll
    for (int ni = 0; ni < 4; ++ni) bn2[ni] = b2[wn + ni * 16 + col];
    const long m0 = (long)blockIdx.y * 128 + wm;
    #pragma unroll
    for (int mi = 0; mi < 4; ++mi) {
        #pragma unroll
        for (int ni = 0; ni < 4; ++ni) {
            long mb = m0 + mi * 16 + quad * 4;
            long n  = wn + ni * 16 + col;
            #pragma unroll
            for (int r = 0; r < 4; ++r) {
                long m = mb + r;
                float v = acc2[mi][ni][r] + bn2[ni];
                v = v > 0.f ? v : 0.f;
                long bb = m >> 13, h = (m >> 10) & 7, t = m & 1023;
                long oi = bb * 1048576 + (n * 8 + h) * 1024 + t;
                outp[oi] = v + xf[oi];
            }
        }
    }
}

// Fused energy + softmax. Grid: (slices, T/32). Block 256 (4 waves).
// R11 ring version (verified): 2-slot counted-vmcnt K staging.
__global__ __launch_bounds__(256, 2)
void attn_fused(const bf16* __restrict__ qk, bf16* __restrict__ attn)
{
    constexpr int PAD = 1032;
    __shared__ __align__(16) char smraw[73728];  // Q 8K + ring 2x32K; Sbuf overlays
    __shared__ float red[2][4][32];
    bf16* Qs = (bf16*)smraw;                  // [32][128]
    bf16* Sbuf = (bf16*)smraw;                // [16][PAD] (overlay, post-energy)

    const int z = blockIdx.x;
    const int zb = z >> 3, zh = z & 7;
    const int t0 = blockIdx.y * 32;
    const int tid = threadIdx.x, w = tid >> 6, lane = tid & 63;
    const int col = lane & 15, quad = lane >> 4;

    const bf16* Qbase = qk + ((long)zb * 1024 + t0) * 2048 + zh * 256;
    const bf16* Kbase = qk + (long)zb * 1024 * 2048 + zh * 256 + 128;

    auto stageK = [&](int slot, int si) {
        bf16* Ks = (bf16*)(smraw + 8192 + slot * 32768);
        const bf16* Kb = Kbase + (long)si * 128 * 2048;
        #pragma unroll
        for (int i = 0; i < 8; ++i) {
            int cbase = i * 256 + w * 64;
            int c = cbase + lane;
            int m = c >> 4, j = c & 15;
            __builtin_amdgcn_global_load_lds(
                (gvoid*)(Kb + (long)m * 2048 + ((j ^ (m & 7)) << 3)),
                (lvoid*)(Ks + cbase * 8), 16, 0, 0);
        }
    };

    #pragma unroll
    for (int i = 0; i < 2; ++i) {
        int cbase = i * 256 + w * 64;
        int c = cbase + lane;
        int m = c >> 4, j = c & 15;
        __builtin_amdgcn_global_load_lds(
            (gvoid*)(Qbase + (long)m * 2048 + ((j ^ (m & 7)) << 3)),
            (lvoid*)(Qs + cbase * 8), 16, 0, 0);
    }
    stageK(0, 0);
    stageK(1, 1);
    asm volatile("s_waitcnt vmcnt(8)" ::: "memory");   // Q + tile0 landed
    __builtin_amdgcn_s_barrier();
    __builtin_amdgcn_sched_barrier(0);

    bf16x8 af[2][4];
    #pragma unroll
    for (int mi = 0; mi < 2; ++mi) {
        int m = mi * 16 + col;
        #pragma unroll
        for (int ki = 0; ki < 4; ++ki)
            af[mi][ki] = *(const bf16x8*)(Qs + m * 128 + ((((ki << 2) + quad) ^ (m & 7)) << 3));
    }

    f32x4 acc[2][16] = {};
    #pragma unroll
    for (int si = 0; si < 8; ++si) {
        const bf16* Ks = (const bf16*)(smraw + 8192 + (si & 1) * 32768);
        bf16x8 bfr[2][4];
        #pragma unroll
        for (int ni = 0; ni < 2; ++ni) {
            int n = w * 32 + ni * 16 + col;
            #pragma unroll
            for (int ki = 0; ki < 4; ++ki)
                bfr[ni][ki] = *(const bf16x8*)(Ks + n * 128 + ((((ki << 2) + quad) ^ (n & 7)) << 3));
        }
        asm volatile("s_waitcnt lgkmcnt(0)" ::: "memory");
        __builtin_amdgcn_sched_barrier(0);
        #pragma unroll
        for (int ki = 0; ki < 4; ++ki)
            #pragma unroll
            for (int mi = 0; mi < 2; ++mi)
                #pragma unroll
                for (int ni = 0; ni < 2; ++ni)
                    acc[mi][si * 2 + ni] = __builtin_amdgcn_mfma_f32_16x16x32_bf16(
                        af[mi][ki], bfr[ni][ki], acc[mi][si * 2 + ni], 0, 0, 0);
        __builtin_amdgcn_s_barrier();              // all waves done reading slot
        if (si + 2 < 8) {
            stageK(si & 1, si + 2);
            asm volatile("s_waitcnt vmcnt(8)" ::: "memory");   // tile si+1 landed
        } else {
            asm volatile("s_waitcnt vmcnt(0)" ::: "memory");
        }
        __builtin_amdgcn_s_barrier();
        __builtin_amdgcn_sched_barrier(0);
    }

    float rmx[2][4], rinv[2][4];
    #pragma unroll
    for (int mi = 0; mi < 2; ++mi)
        #pragma unroll
        for (int r = 0; r < 4; ++r) {
            float mx = acc[mi][0][r];
            #pragma unroll
            for (int j = 1; j < 16; ++j) mx = fmaxf(mx, acc[mi][j][r]);
            #pragma unroll
            for (int off = 1; off < 16; off <<= 1) mx = fmaxf(mx, __shfl_xor(mx, off, 64));
            rmx[mi][r] = mx;
        }
    if (col == 0) {
        #pragma unroll
        for (int mi = 0; mi < 2; ++mi)
            #pragma unroll
            for (int r = 0; r < 4; ++r)
                red[0][w][mi * 16 + quad * 4 + r] = rmx[mi][r];
    }
    __syncthreads();
    #pragma unroll
    for (int mi = 0; mi < 2; ++mi)
        #pragma unroll
        for (int r = 0; r < 4; ++r) {
            int row = mi * 16 + quad * 4 + r;
            rmx[mi][r] = fmaxf(fmaxf(red[0][0][row], red[0][1][row]),
                               fmaxf(red[0][2][row], red[0][3][row]));
        }
    #pragma unroll
    for (int mi = 0; mi < 2; ++mi)
        #pragma unroll
        for (int r = 0; r < 4; ++r) {
            float s = 0.f;
            #pragma unroll
            for (int j = 0; j < 16; ++j) {
                acc[mi][j][r] = __expf(acc[mi][j][r] - rmx[mi][r]);
                s += acc[mi][j][r];
            }
            #pragma unroll
            for (int off = 1; off < 16; off <<= 1) s += __shfl_xor(s, off, 64);
            rinv[mi][r] = s;
        }
    if (col == 0) {
        #pragma unroll
        for (int mi = 0; mi < 2; ++mi)
            #pragma unroll
            for (int r = 0; r < 4; ++r)
                red[1][w][mi * 16 + quad * 4 + r] = rinv[mi][r];
    }
    __syncthreads();
    #pragma unroll
    for (int mi = 0; mi < 2; ++mi)
        #pragma unroll
        for (int r = 0; r < 4; ++r) {
            int row = mi * 16 + quad * 4 + r;
            float s4 = red[1][0][row] + red[1][1][row] + red[1][2][row] + red[1][3][row];
            rinv[mi][r] = 1.0f / s4;
        }

    bf16* dst = attn + ((long)(zb * 8 + zh)) * 1048576 + (long)t0 * 1024;
    #pragma unroll
    for (int mi = 0; mi < 2; ++mi) {
        __syncthreads();
        #pragma unroll
        for (int j = 0; j < 16; ++j) {
            int colb = (j >> 1) * 128 + w * 32 + (j & 1) * 16 + col;
            #pragma unroll
            for (int r = 0; r < 4; ++r) {
                int rowh = quad * 4 + r;
                Sbuf[rowh * PAD + colb] = __float2bfloat16(acc[mi][j][r] * rinv[mi][r]);
            }
        }
        __syncthreads();
        #pragma unroll
        for (int i = 0; i < 8; ++i) {
            int c = i * 256 + tid;             // 16 rows x 128 chunks
            int rowh = c >> 7, jj = c & 127;
            bf16x8 vv = *(const bf16x8*)(Sbuf + rowh * PAD + jj * 8);
            *(bf16x8*)(dst + (long)(mi * 16 + rowh) * 1024 + jj * 8) = vv;
        }
    }
}

// x (B,C,T) f32 -> xt (B,T,C) bf16, 32x32 LDS tiles
__global__ __launch_bounds__(256)
void transpose_cast_x(const float* __restrict__ x, bf16* __restrict__ xt)
{
    __shared__ float tile[32][33];
    int b = blockIdx.z;
    int c0 = blockIdx.y * 32, t0 = blockIdx.x * 32;
    int tx = threadIdx.x & 31, ty = threadIdx.x >> 5;  // ty 0..7
    const float* xb = x + (long)b * 1024 * 1024;
    #pragma unroll
    for (int i = 0; i < 4; ++i) {
        int c = ty + i * 8;
        tile[c][tx] = xb[(long)(c0 + c) * 1024 + t0 + tx];
    }
    __syncthreads();
    bf16* xtb = xt + (long)b * 1024 * 1024;
    #pragma unroll
    for (int i = 0; i < 4; ++i) {
        int t = ty + i * 8;
        xtb[(long)(t0 + t) * 1024 + c0 + tx] = __float2bfloat16(tile[tx][t]);
    }
}

__global__ __launch_bounds__(256)
void cast_f2b(const float* __restrict__ in, bf16* __restrict__ out, long n)
{
    long i = (long)blockIdx.x * 256 + threadIdx.x;
    long stride = (long)gridDim.x * 256;
    for (; i < n; i += stride) out[i] = __float2bfloat16(in[i]);
}

// Build stacked qk weight (2048 x 1024 bf16)
__global__ __launch_bounds__(256)
void build_wqk(const float* __restrict__ Wq, const float* __restrict__ Wk,
               const float* __restrict__ bq, const float* __restrict__ bk,
               bf16* __restrict__ Wqk, float* __restrict__ biasqk)
{
    long i = (long)blockIdx.x * 256 + threadIdx.x;   // 2048*1024 total
    long r = i >> 10, c = i & 1023;
    long h = r >> 8, rr = r & 255;
    float v = (rr < 128) ? Wq[(h * 128 + rr) * 1024 + c]
                         : Wk[(h * 128 + (rr - 128)) * 1024 + c];
    Wqk[i] = __float2bfloat16(v);
    if (c == 0)
        biasqk[r] = (rr < 128) ? bq[h * 128 + rr] : bk[h * 128 + rr - 128];
}

extern "C" void kernel_launch(void* const* d_in, const int* in_sizes, int n_in,
                              void* d_out, int out_size, void* d_ws, size_t ws_size,
                              hipStream_t stream)
{
    const float* x     = (const float*)d_in[0];
    const float* Wq    = (const float*)d_in[1];
    const float* bq    = (const float*)d_in[2];
    const float* Wk    = (const float*)d_in[3];
    const float* bk    = (const float*)d_in[4];
    const float* Wv    = (const float*)d_in[5];
    const float* bv    = (const float*)d_in[6];
    const float* gamma = (const float*)d_in[7];
    const float* W1    = (const float*)d_in[8];
    const float* b1    = (const float*)d_in[9];
    const float* W2    = (const float*)d_in[10];
    const float* b2    = (const float*)d_in[11];
    float* out = (float*)d_out;

    char* base = (char*)d_ws;
    const long MB = 1048576;
    bf16*  xt   = (bf16*)(base);
    bf16*  Wvb  = (bf16*)(base + 16 * MB);
    bf16*  vbuf = (bf16*)(base + 32 * MB);
    bf16*  Wqk  = (bf16*)(base + 32 * MB);          // dead after qk-proj
    float* bqk  = (float*)(base + 36 * MB);         // dead after qk-proj
    bf16*  attb = (bf16*)(base + 96 * MB);
    bf16*  W1b  = (bf16*)(base + 96 * MB);          // post-O overlay, re-cast per pass
    bf16*  W2b  = (bf16*)(base + 96 * MB + 524288);
    bf16*  ot   = (bf16*)(base + 160 * MB);
    bf16*  qkt  = (bf16*)(base + 224 * MB);

    dim3 blk(256);
    transpose_cast_x<<<dim3(32, 32, 8), blk, 0, stream>>>(x, xt);
    build_wqk<<<8192, blk, 0, stream>>>(Wq, Wk, bq, bk, Wqk, bqk);
    cast_f2b<<<4096, blk, 0, stream>>>(Wv, Wvb, 8192ll * 1024);

    const long M1 = 1048576, M2 = 2097152, M8 = 8388608;

    // qk_t: M=8192 (b,t), N=2048 (h*256+o), K=1024 — gemm256 QKLAY (512 blocks)
    gemm256<1, 1><<<dim3(16, 32, 1), blk, 0, stream>>>(
        xt, 1024, 0, 0, Wqk, 1024, 0, 0, qkt, 2048, 0, 0, 1024,
        bqk, 0, nullptr, nullptr, 0);

    for (int q = 0; q < 2; ++q) {
        const long b0 = (long)q * 4;
        const bf16* xtq = xt + b0 * M1;
        // v(zb,zh;c,s) = Wv[zh](c,ci) . xt(b0+zb;s,ci)^T + bv[zh,c]
        gemm256<0, 0><<<dim3(64, 4, 4), blk, 0, stream>>>(
            Wvb, 1024, 0, M1, xtq, 1024, M1, 0, vbuf, 1024, M8, M1, 1024,
            bv, 1024, nullptr, nullptr, 0);
        // fused E + softmax -> attb bf16 (1024 blocks)
        attn_fused<<<dim3(32, 32, 1), blk, 0, stream>>>(
            qkt + b0 * M2, attb);
        // heads_t(zb,zh;t,c) = gamma[zh]*(attn(t,s).v(c,s)^T) + xt(b0+zb;t,c)
        gemm256<3, 0><<<dim3(64, 4, 4), blk, 0, stream>>>(
            attb, 1024, M8, M1, vbuf, 1024, M8, M1,
            ot, 1024, M8, M1, 1024,
            nullptr, 0, gamma, xtq, 1024);
        // attb dead: cast FC weights into its region (re-done each pass)
        cast_f2b<<<512, blk, 0, stream>>>(W1, W1b, 128 * 1024);
        cast_f2b<<<64, blk, 0, stream>>>(W2, W2b, 128 * 128);
        // fc1+fc2 fused (ring): M=32768 rows, 256 blocks of 128 rows
        fc_fused<<<dim3(1, 256, 1), blk, 0, stream>>>(
            ot, W1b, W2b, b1, b2, out + b0 * M1, x + b0 * M1);
    }
}

// Round 14
// 640.288 us; speedup vs baseline: 1.0076x; 1.0048x over previous
//
#include <hip/hip_runtime.h>
#include <hip/hip_bf16.h>

typedef __hip_bfloat16 bf16;
typedef __attribute__((ext_vector_type(8))) __bf16 bf16x8;
typedef __attribute__((ext_vector_type(4))) float f32x4;

typedef const __attribute__((address_space(1))) void gvoid;
typedef __attribute__((address_space(3))) void lvoid;

// ---------------------------------------------------------------------------
// gemm256 (R8/R11/R13-verified, 85.5 us): counted-vmcnt ring-pipelined NT GEMM,
// BK=32, 2 blocks/CU, 4 waves x (64M x 128N) per wave (acc 4x8).
// Ring: 3 slots x (A 256x32 + B 128x32) bf16 = 72 KB.
// Pipeline: compute tile t from slot t%3 while t+2's loads fly; vmcnt(6)
// before the barrier drains t+1's 6 loads/thread only. 1 barrier/K-tile.
// LDS swizzle: row-pair XOR (verified 0-conflict R6-R13).
// Plateau: 800 TF across 4 tile/wave configs; 8-phase recon slower (R10).
// MODE 0: acc + bias[zh*sBiasZ+m] (v-proj); MODE 3: gamma*acc + xt (PV);
// MODE 1: acc + bias[n] (qk-proj, QKLAY=1).
// ---------------------------------------------------------------------------
template<int MODE, int QKLAY>
__global__ __launch_bounds__(256, 2)
void gemm256(const bf16* __restrict__ A, long lda, long sAb, long sAh,
             const bf16* __restrict__ B, long ldb, long sBb, long sBh,
             void* __restrict__ Cv, long ldc, long sCb, long sCh,
             int K,
             const float* __restrict__ bias, long sBiasZ,
             const float* __restrict__ gamma,
             const bf16* __restrict__ xt, long ldxt)
{
    __shared__ bf16 ring[3][(256 + 128) * 32];   // 73728 B
    const int nt4 = QKLAY ? blockIdx.x : (blockIdx.x >> 3);
    const int zh  = QKLAY ? 0 : (blockIdx.x & 7);
    const int zb  = QKLAY ? 0 : blockIdx.z;
    const bf16* Ab = A + (long)zb * sAb + (long)zh * sAh + (long)blockIdx.y * 256 * lda;
    const bf16* Bb = B + (long)zb * sBb + (long)zh * sBh + (long)nt4 * 128 * ldb;
    const int tid = threadIdx.x;
    const int wave = tid >> 6, lane = tid & 63;
    const int col = lane & 15, quad = lane >> 4;
    const int wm = wave * 64;                    // per-wave 64 rows, full 128 cols

    const bf16* aAddr[4];
    const bf16* bAddr[2];
    int aDst[4], bDst[2];
    #pragma unroll
    for (int i = 0; i < 4; ++i) {
        int cbase = i * 256 + wave * 64;         // wave-uniform chunk base
        int c = cbase + lane;
        int p = c >> 3;
        int sp = (c & 7) ^ (p & 7);
        int m = 2 * p + (sp >> 2);
        int j = sp & 3;
        aAddr[i] = Ab + (long)m * lda + (j << 3);
        aDst[i] = cbase * 8;
    }
    #pragma unroll
    for (int i = 0; i < 2; ++i) {
        int cbase = i * 256 + wave * 64;
        int c = cbase + lane;
        int p = c >> 3;
        int sp = (c & 7) ^ (p & 7);
        int m = 2 * p + (sp >> 2);
        int j = sp & 3;
        bAddr[i] = Bb + (long)m * ldb + (j << 3);
        bDst[i] = 8192 + cbase * 8;
    }

    int offA[4], offB[8];
    #pragma unroll
    for (int mi = 0; mi < 4; ++mi) {
        int m = wm + mi * 16 + col;
        int p = m >> 1;
        int s = (quad | ((m & 1) << 2)) ^ (p & 7);
        offA[mi] = p * 64 + s * 8;
    }
    #pragma unroll
    for (int ni = 0; ni < 8; ++ni) {
        int n = ni * 16 + col;
        int pn = n >> 1;
        int sn = (quad | ((n & 1) << 2)) ^ (pn & 7);
        offB[ni] = 8192 + pn * 64 + sn * 8;
    }

    f32x4 acc[4][8] = {};

    auto STAGE = [&](int rb) {
        bf16* base = &ring[rb][0];
        #pragma unroll
        for (int i = 0; i < 4; ++i) {
            __builtin_amdgcn_global_load_lds((gvoid*)aAddr[i], (lvoid*)(base + aDst[i]), 16, 0, 0);
            aAddr[i] += 32;
        }
        #pragma unroll
        for (int i = 0; i < 2; ++i) {
            __builtin_amdgcn_global_load_lds((gvoid*)bAddr[i], (lvoid*)(base + bDst[i]), 16, 0, 0);
            bAddr[i] += 32;
        }
    };

    const int NT = K >> 5;                        // 32 K-tiles
    STAGE(0);
    STAGE(1);                                     // 12 loads in flight
    asm volatile("s_waitcnt vmcnt(6)" ::: "memory");
    __builtin_amdgcn_s_barrier();
    __builtin_amdgcn_sched_barrier(0);

    int rc = 0;
    for (int t = 0; t < NT; ++t) {
        int r2 = rc + 2; if (r2 >= 3) r2 -= 3;
        if (t + 2 < NT) STAGE(r2);                // issue tile t+2 early
        const bf16* buf = &ring[rc][0];
        bf16x8 af[4], bfr[8];
        #pragma unroll
        for (int mi = 0; mi < 4; ++mi)
            af[mi] = *(const bf16x8*)(buf + offA[mi]);
        #pragma unroll
        for (int ni = 0; ni < 8; ++ni)
            bfr[ni] = *(const bf16x8*)(buf + offB[ni]);
        #pragma unroll
        for (int mi = 0; mi < 4; ++mi)
            #pragma unroll
            for (int ni = 0; ni < 8; ++ni)
                acc[mi][ni] = __builtin_amdgcn_mfma_f32_16x16x32_bf16(
                    af[mi], bfr[ni], acc[mi][ni], 0, 0, 0);
        if (t + 2 < NT)
            asm volatile("s_waitcnt vmcnt(6)" ::: "memory");
        else if (t + 1 < NT)
            asm volatile("s_waitcnt vmcnt(0)" ::: "memory");
        if (t + 1 < NT) {
            __builtin_amdgcn_s_barrier();
            __builtin_amdgcn_sched_barrier(0);
        }
        rc = rc + 1; if (rc >= 3) rc -= 3;
    }

    const long m0 = (long)blockIdx.y * 256 + wm;
    const long n0 = (long)nt4 * 128;
    float g = 0.f;
    if (MODE == 3) g = gamma[zh];
    float bn[8];
    if constexpr (MODE == 1) {
        #pragma unroll
        for (int ni = 0; ni < 8; ++ni)
            bn[ni] = bias[n0 + ni * 16 + col];
    }
    #pragma unroll
    for (int mi = 0; mi < 4; ++mi) {
        #pragma unroll
        for (int ni = 0; ni < 8; ++ni) {
            long mb = m0 + mi * 16 + quad * 4;
            long n  = n0 + ni * 16 + col;
            if constexpr (MODE == 0) {
                bf16* cp = (bf16*)Cv + (long)zb * sCb + (long)zh * sCh + mb * ldc + n;
                const float* bp = bias + zh * sBiasZ + mb;
                #pragma unroll
                for (int r = 0; r < 4; ++r) {
                    *cp = __float2bfloat16(acc[mi][ni][r] + bp[r]);
                    cp += ldc;
                }
            } else if constexpr (MODE == 1) {
                bf16* cp = (bf16*)Cv + mb * ldc + n;
                #pragma unroll
                for (int r = 0; r < 4; ++r) {
                    *cp = __float2bfloat16(acc[mi][ni][r] + bn[ni]);
                    cp += ldc;
                }
            } else {
                bf16* cp = (bf16*)Cv + (long)zb * sCb + (long)zh * sCh + mb * ldc + n;
                const bf16* xp = xt + (long)zb * 1048576 + mb * ldxt + n;
                #pragma unroll
                for (int r = 0; r < 4; ++r) {
                    float xv = __bfloat162float(*xp);
                    *cp = __float2bfloat16(g * acc[mi][ni][r] + xv);
                    cp += ldc;
                    xp += ldxt;
                }
            }
        }
    }
}

// ---------------------------------------------------------------------------
// fc_fused (R13-verified): fc1 + fc2 in one kernel, fc1 K-loop ring-pipelined.
// ---------------------------------------------------------------------------
__global__ __launch_bounds__(256, 2)
void fc_fused(const bf16* __restrict__ ot,
              const bf16* __restrict__ W1b,
              const bf16* __restrict__ W2b,
              const float* __restrict__ b1,
              const float* __restrict__ b2,
              float* __restrict__ outp,
              const float* __restrict__ xf)
{
    __shared__ bf16 ring[3][128 * 32 * 2];       // A (4096 el) + B (4096 el) per slot
    __shared__ bf16 y1[128 * 128];               // 32 KB
    const int tid = threadIdx.x;
    const int wave = tid >> 6, lane = tid & 63;
    const int col = lane & 15, quad = lane >> 4;
    const int wm = (wave & 1) * 64, wn = (wave >> 1) * 64;
    const bf16* Ab = ot + (long)blockIdx.y * 128 * 1024;

    const bf16* aAddr[2];
    const bf16* bAddr[2];
    int aDst[2], bDst[2];
    #pragma unroll
    for (int i = 0; i < 2; ++i) {
        int cbase = i * 256 + wave * 64;
        int c = cbase + lane;
        int p = c >> 3;
        int sp = (c & 7) ^ (p & 7);
        int m = 2 * p + (sp >> 2);
        int j = sp & 3;
        aAddr[i] = Ab + (long)m * 1024 + (j << 3);
        aDst[i] = cbase * 8;
        bAddr[i] = W1b + (long)m * 1024 + (j << 3);
        bDst[i] = 4096 + cbase * 8;
    }

    int offA[4], offB[4];
    #pragma unroll
    for (int mi = 0; mi < 4; ++mi) {
        int m = wm + mi * 16 + col;
        int p = m >> 1;
        int s = (quad | ((m & 1) << 2)) ^ (p & 7);
        offA[mi] = p * 64 + s * 8;
        int n = wn + mi * 16 + col;
        int pn = n >> 1;
        int sn = (quad | ((n & 1) << 2)) ^ (pn & 7);
        offB[mi] = 4096 + pn * 64 + sn * 8;
    }

    auto STAGE = [&](int rb) {
        bf16* base = &ring[rb][0];
        #pragma unroll
        for (int i = 0; i < 2; ++i) {
            __builtin_amdgcn_global_load_lds((gvoid*)aAddr[i], (lvoid*)(base + aDst[i]), 16, 0, 0);
            aAddr[i] += 32;
        }
        #pragma unroll
        for (int i = 0; i < 2; ++i) {
            __builtin_amdgcn_global_load_lds((gvoid*)bAddr[i], (lvoid*)(base + bDst[i]), 16, 0, 0);
            bAddr[i] += 32;
        }
    };

    f32x4 acc[4][4] = {};
    const int NT = 32;                            // K=1024, BK=32
    STAGE(0);
    STAGE(1);                                     // 8 loads in flight
    asm volatile("s_waitcnt vmcnt(4)" ::: "memory");
    __builtin_amdgcn_s_barrier();
    __builtin_amdgcn_sched_barrier(0);

    int rc = 0;
    for (int t = 0; t < NT; ++t) {
        int r2 = rc + 2; if (r2 >= 3) r2 -= 3;
        if (t + 2 < NT) STAGE(r2);
        const bf16* buf = &ring[rc][0];
        bf16x8 af[4], bfr[4];
        #pragma unroll
        for (int mi = 0; mi < 4; ++mi)
            af[mi] = *(const bf16x8*)(buf + offA[mi]);
        #pragma unroll
        for (int ni = 0; ni < 4; ++ni)
            bfr[ni] = *(const bf16x8*)(buf + offB[ni]);
        #pragma unroll
        for (int mi = 0; mi < 4; ++mi)
            #pragma unroll
            for (int ni = 0; ni < 4; ++ni)
                acc[mi][ni] = __builtin_amdgcn_mfma_f32_16x16x32_bf16(
                    af[mi], bfr[ni], acc[mi][ni], 0, 0, 0);
        if (t + 2 < NT)
            asm volatile("s_waitcnt vmcnt(4)" ::: "memory");
        else if (t + 1 < NT)
            asm volatile("s_waitcnt vmcnt(0)" ::: "memory");
        if (t + 1 < NT) {
            __builtin_amdgcn_s_barrier();
            __builtin_amdgcn_sched_barrier(0);
        }
        rc = rc + 1; if (rc >= 3) rc -= 3;
    }

    float bn1[4];
    #pragma unroll
    for (int ni = 0; ni < 4; ++ni) bn1[ni] = b1[wn + ni * 16 + col];
    #pragma unroll
    for (int mi = 0; mi < 4; ++mi) {
        #pragma unroll
        for (int ni = 0; ni < 4; ++ni) {
            int mb = wm + mi * 16 + quad * 4;
            int n  = wn + ni * 16 + col;
            int nc = n >> 3, nr = n & 7;
            #pragma unroll
            for (int r = 0; r < 4; ++r) {
                float v = acc[mi][ni][r] + bn1[ni];
                v = v > 0.f ? v : 0.f;
                int m = mb + r;
                y1[m * 128 + (((nc) ^ (m & 7)) << 3) + nr] = __float2bfloat16(v);
            }
        }
    }
    __syncthreads();

    f32x4 acc2[4][4] = {};
    #pragma unroll
    for (int kk = 0; kk < 4; ++kk) {
        int kq = kk * 4 + quad;
        bf16x8 af2[4], bf2[4];
        #pragma unroll
        for (int mi = 0; mi < 4; ++mi) {
            int m = wm + mi * 16 + col;
            af2[mi] = *(const bf16x8*)(y1 + m * 128 + ((kq ^ (m & 7)) << 3));
        }
        #pragma unroll
        for (int ni = 0; ni < 4; ++ni) {
            int n = wn + ni * 16 + col;
            bf2[ni] = *(const bf16x8*)(W2b + n * 128 + kq * 8);
        }
        #pragma unroll
        for (int mi = 0; mi < 4; ++mi)
            #pragma unroll
            for (int ni = 0; ni < 4; ++ni)
                acc2[mi][ni] = __builtin_amdgcn_mfma_f32_16x16x32_bf16(
                    af2[mi], bf2[ni], acc2[mi][ni], 0, 0, 0);
    }

    float bn2[4];
    #pragma unroll
    for (int ni = 0; ni < 4; ++ni) bn2[ni] = b2[wn + ni * 16 + col];
    const long m0 = (long)blockIdx.y * 128 + wm;
    #pragma unroll
    for (int mi = 0; mi < 4; ++mi) {
        #pragma unroll
        for (int ni = 0; ni < 4; ++ni) {
            long mb = m0 + mi * 16 + quad * 4;
            long n  = wn + ni * 16 + col;
            #pragma unroll
            for (int r = 0; r < 4; ++r) {
                long m = mb + r;
                float v = acc2[mi][ni][r] + bn2[ni];
                v = v > 0.f ? v : 0.f;
                long bb = m >> 13, h = (m >> 10) & 7, t = m & 1023;
                long oi = bb * 1048576 + (n * 8 + h) * 1024 + t;
                outp[oi] = v + xf[oi];
            }
        }
    }
}

// Fused energy + softmax. Grid: (T/32, slices). Block 256 (4 waves).
// R14: grid roles swapped — t0 in blockIdx.x (fast), slice in blockIdx.y —
// so 32 consecutive blocks share one (zb,zh) K-slice (256 KB) -> K re-reads
// become same-XCD L2 hits (R4->R5 PV locality fix, applied to attn).
// R11 ring (verified): 2-slot counted-vmcnt K staging.
__global__ __launch_bounds__(256, 2)
void attn_fused(const bf16* __restrict__ qk, bf16* __restrict__ attn)
{
    constexpr int PAD = 1032;
    __shared__ __align__(16) char smraw[73728];  // Q 8K + ring 2x32K; Sbuf overlays
    __shared__ float red[2][4][32];
    bf16* Qs = (bf16*)smraw;                  // [32][128]
    bf16* Sbuf = (bf16*)smraw;                // [16][PAD] (overlay, post-energy)

    const int z = blockIdx.y;                 // R14: slice in y (slow)
    const int zb = z >> 3, zh = z & 7;
    const int t0 = blockIdx.x * 32;           // R14: t0 in x (fast)
    const int tid = threadIdx.x, w = tid >> 6, lane = tid & 63;
    const int col = lane & 15, quad = lane >> 4;

    const bf16* Qbase = qk + ((long)zb * 1024 + t0) * 2048 + zh * 256;
    const bf16* Kbase = qk + (long)zb * 1024 * 2048 + zh * 256 + 128;

    auto stageK = [&](int slot, int si) {
        bf16* Ks = (bf16*)(smraw + 8192 + slot * 32768);
        const bf16* Kb = Kbase + (long)si * 128 * 2048;
        #pragma unroll
        for (int i = 0; i < 8; ++i) {
            int cbase = i * 256 + w * 64;
            int c = cbase + lane;
            int m = c >> 4, j = c & 15;
            __builtin_amdgcn_global_load_lds(
                (gvoid*)(Kb + (long)m * 2048 + ((j ^ (m & 7)) << 3)),
                (lvoid*)(Ks + cbase * 8), 16, 0, 0);
        }
    };

    #pragma unroll
    for (int i = 0; i < 2; ++i) {
        int cbase = i * 256 + w * 64;
        int c = cbase + lane;
        int m = c >> 4, j = c & 15;
        __builtin_amdgcn_global_load_lds(
            (gvoid*)(Qbase + (long)m * 2048 + ((j ^ (m & 7)) << 3)),
            (lvoid*)(Qs + cbase * 8), 16, 0, 0);
    }
    stageK(0, 0);
    stageK(1, 1);
    asm volatile("s_waitcnt vmcnt(8)" ::: "memory");   // Q + tile0 landed
    __builtin_amdgcn_s_barrier();
    __builtin_amdgcn_sched_barrier(0);

    bf16x8 af[2][4];
    #pragma unroll
    for (int mi = 0; mi < 2; ++mi) {
        int m = mi * 16 + col;
        #pragma unroll
        for (int ki = 0; ki < 4; ++ki)
            af[mi][ki] = *(const bf16x8*)(Qs + m * 128 + ((((ki << 2) + quad) ^ (m & 7)) << 3));
    }

    f32x4 acc[2][16] = {};
    #pragma unroll
    for (int si = 0; si < 8; ++si) {
        const bf16* Ks = (const bf16*)(smraw + 8192 + (si & 1) * 32768);
        bf16x8 bfr[2][4];
        #pragma unroll
        for (int ni = 0; ni < 2; ++ni) {
            int n = w * 32 + ni * 16 + col;
            #pragma unroll
            for (int ki = 0; ki < 4; ++ki)
                bfr[ni][ki] = *(const bf16x8*)(Ks + n * 128 + ((((ki << 2) + quad) ^ (n & 7)) << 3));
        }
        asm volatile("s_waitcnt lgkmcnt(0)" ::: "memory");
        __builtin_amdgcn_sched_barrier(0);
        #pragma unroll
        for (int ki = 0; ki < 4; ++ki)
            #pragma unroll
            for (int mi = 0; mi < 2; ++mi)
                #pragma unroll
                for (int ni = 0; ni < 2; ++ni)
                    acc[mi][si * 2 + ni] = __builtin_amdgcn_mfma_f32_16x16x32_bf16(
                        af[mi][ki], bfr[ni][ki], acc[mi][si * 2 + ni], 0, 0, 0);
        __builtin_amdgcn_s_barrier();              // all waves done reading slot
        if (si + 2 < 8) {
            stageK(si & 1, si + 2);
            asm volatile("s_waitcnt vmcnt(8)" ::: "memory");   // tile si+1 landed
        } else {
            asm volatile("s_waitcnt vmcnt(0)" ::: "memory");
        }
        __builtin_amdgcn_s_barrier();
        __builtin_amdgcn_sched_barrier(0);
    }

    float rmx[2][4], rinv[2][4];
    #pragma unroll
    for (int mi = 0; mi < 2; ++mi)
        #pragma unroll
        for (int r = 0; r < 4; ++r) {
            float mx = acc[mi][0][r];
            #pragma unroll
            for (int j = 1; j < 16; ++j) mx = fmaxf(mx, acc[mi][j][r]);
            #pragma unroll
            for (int off = 1; off < 16; off <<= 1) mx = fmaxf(mx, __shfl_xor(mx, off, 64));
            rmx[mi][r] = mx;
        }
    if (col == 0) {
        #pragma unroll
        for (int mi = 0; mi < 2; ++mi)
            #pragma unroll
            for (int r = 0; r < 4; ++r)
                red[0][w][mi * 16 + quad * 4 + r] = rmx[mi][r];
    }
    __syncthreads();
    #pragma unroll
    for (int mi = 0; mi < 2; ++mi)
        #pragma unroll
        for (int r = 0; r < 4; ++r) {
            int row = mi * 16 + quad * 4 + r;
            rmx[mi][r] = fmaxf(fmaxf(red[0][0][row], red[0][1][row]),
                               fmaxf(red[0][2][row], red[0][3][row]));
        }
    #pragma unroll
    for (int mi = 0; mi < 2; ++mi)
        #pragma unroll
        for (int r = 0; r < 4; ++r) {
            float s = 0.f;
            #pragma unroll
            for (int j = 0; j < 16; ++j) {
                acc[mi][j][r] = __expf(acc[mi][j][r] - rmx[mi][r]);
                s += acc[mi][j][r];
            }
            #pragma unroll
            for (int off = 1; off < 16; off <<= 1) s += __shfl_xor(s, off, 64);
            rinv[mi][r] = s;
        }
    if (col == 0) {
        #pragma unroll
        for (int mi = 0; mi < 2; ++mi)
            #pragma unroll
            for (int r = 0; r < 4; ++r)
                red[1][w][mi * 16 + quad * 4 + r] = rinv[mi][r];
    }
    __syncthreads();
    #pragma unroll
    for (int mi = 0; mi < 2; ++mi)
        #pragma unroll
        for (int r = 0; r < 4; ++r) {
            int row = mi * 16 + quad * 4 + r;
            float s4 = red[1][0][row] + red[1][1][row] + red[1][2][row] + red[1][3][row];
            rinv[mi][r] = 1.0f / s4;
        }

    bf16* dst = attn + ((long)(zb * 8 + zh)) * 1048576 + (long)t0 * 1024;
    #pragma unroll
    for (int mi = 0; mi < 2; ++mi) {
        __syncthreads();
        #pragma unroll
        for (int j = 0; j < 16; ++j) {
            int colb = (j >> 1) * 128 + w * 32 + (j & 1) * 16 + col;
            #pragma unroll
            for (int r = 0; r < 4; ++r) {
                int rowh = quad * 4 + r;
                Sbuf[rowh * PAD + colb] = __float2bfloat16(acc[mi][j][r] * rinv[mi][r]);
            }
        }
        __syncthreads();
        #pragma unroll
        for (int i = 0; i < 8; ++i) {
            int c = i * 256 + tid;             // 16 rows x 128 chunks
            int rowh = c >> 7, jj = c & 127;
            bf16x8 vv = *(const bf16x8*)(Sbuf + rowh * PAD + jj * 8);
            *(bf16x8*)(dst + (long)(mi * 16 + rowh) * 1024 + jj * 8) = vv;
        }
    }
}

// x (B,C,T) f32 -> xt (B,T,C) bf16, 32x32 LDS tiles
__global__ __launch_bounds__(256)
void transpose_cast_x(const float* __restrict__ x, bf16* __restrict__ xt)
{
    __shared__ float tile[32][33];
    int b = blockIdx.z;
    int c0 = blockIdx.y * 32, t0 = blockIdx.x * 32;
    int tx = threadIdx.x & 31, ty = threadIdx.x >> 5;  // ty 0..7
    const float* xb = x + (long)b * 1024 * 1024;
    #pragma unroll
    for (int i = 0; i < 4; ++i) {
        int c = ty + i * 8;
        tile[c][tx] = xb[(long)(c0 + c) * 1024 + t0 + tx];
    }
    __syncthreads();
    bf16* xtb = xt + (long)b * 1024 * 1024;
    #pragma unroll
    for (int i = 0; i < 4; ++i) {
        int t = ty + i * 8;
        xtb[(long)(t0 + t) * 1024 + c0 + tx] = __float2bfloat16(tile[tx][t]);
    }
}

__global__ __launch_bounds__(256)
void cast_f2b(const float* __restrict__ in, bf16* __restrict__ out, long n)
{
    long i = (long)blockIdx.x * 256 + threadIdx.x;
    long stride = (long)gridDim.x * 256;
    for (; i < n; i += stride) out[i] = __float2bfloat16(in[i]);
}

// Build stacked qk weight (2048 x 1024 bf16)
__global__ __launch_bounds__(256)
void build_wqk(const float* __restrict__ Wq, const float* __restrict__ Wk,
               const float* __restrict__ bq, const float* __restrict__ bk,
               bf16* __restrict__ Wqk, float* __restrict__ biasqk)
{
    long i = (long)blockIdx.x * 256 + threadIdx.x;   // 2048*1024 total
    long r = i >> 10, c = i & 1023;
    long h = r >> 8, rr = r & 255;
    float v = (rr < 128) ? Wq[(h * 128 + rr) * 1024 + c]
                         : Wk[(h * 128 + (rr - 128)) * 1024 + c];
    Wqk[i] = __float2bfloat16(v);
    if (c == 0)
        biasqk[r] = (rr < 128) ? bq[h * 128 + rr] : bk[h * 128 + rr - 128];
}

extern "C" void kernel_launch(void* const* d_in, const int* in_sizes, int n_in,
                              void* d_out, int out_size, void* d_ws, size_t ws_size,
                              hipStream_t stream)
{
    const float* x     = (const float*)d_in[0];
    const float* Wq    = (const float*)d_in[1];
    const float* bq    = (const float*)d_in[2];
    const float* Wk    = (const float*)d_in[3];
    const float* bk    = (const float*)d_in[4];
    const float* Wv    = (const float*)d_in[5];
    const float* bv    = (const float*)d_in[6];
    const float* gamma = (const float*)d_in[7];
    const float* W1    = (const float*)d_in[8];
    const float* b1    = (const float*)d_in[9];
    const float* W2    = (const float*)d_in[10];
    const float* b2    = (const float*)d_in[11];
    float* out = (float*)d_out;

    char* base = (char*)d_ws;
    const long MB = 1048576;
    bf16*  xt   = (bf16*)(base);
    bf16*  Wvb  = (bf16*)(base + 16 * MB);
    bf16*  vbuf = (bf16*)(base + 32 * MB);
    bf16*  Wqk  = (bf16*)(base + 32 * MB);          // dead after qk-proj
    float* bqk  = (float*)(base + 36 * MB);         // dead after qk-proj
    bf16*  attb = (bf16*)(base + 96 * MB);
    bf16*  W1b  = (bf16*)(base + 96 * MB);          // post-O overlay, re-cast per pass
    bf16*  W2b  = (bf16*)(base + 96 * MB + 524288);
    bf16*  ot   = (bf16*)(base + 160 * MB);
    bf16*  qkt  = (bf16*)(base + 224 * MB);

    dim3 blk(256);
    transpose_cast_x<<<dim3(32, 32, 8), blk, 0, stream>>>(x, xt);
    build_wqk<<<8192, blk, 0, stream>>>(Wq, Wk, bq, bk, Wqk, bqk);
    cast_f2b<<<4096, blk, 0, stream>>>(Wv, Wvb, 8192ll * 1024);

    const long M1 = 1048576, M2 = 2097152, M8 = 8388608;

    // qk_t: M=8192 (b,t), N=2048 (h*256+o), K=1024 — gemm256 QKLAY (512 blocks)
    gemm256<1, 1><<<dim3(16, 32, 1), blk, 0, stream>>>(
        xt, 1024, 0, 0, Wqk, 1024, 0, 0, qkt, 2048, 0, 0, 1024,
        bqk, 0, nullptr, nullptr, 0);

    for (int q = 0; q < 2; ++q) {
        const long b0 = (long)q * 4;
        const bf16* xtq = xt + b0 * M1;
        // v(zb,zh;c,s) = Wv[zh](c,ci) . xt(b0+zb;s,ci)^T + bv[zh,c]
        gemm256<0, 0><<<dim3(64, 4, 4), blk, 0, stream>>>(
            Wvb, 1024, 0, M1, xtq, 1024, M1, 0, vbuf, 1024, M8, M1, 1024,
            bv, 1024, nullptr, nullptr, 0);
        // fused E + softmax -> attb bf16 (1024 blocks; t0 fast, slice slow)
        attn_fused<<<dim3(32, 32, 1), blk, 0, stream>>>(
            qkt + b0 * M2, attb);
        // heads_t(zb,zh;t,c) = gamma[zh]*(attn(t,s).v(c,s)^T) + xt(b0+zb;t,c)
        gemm256<3, 0><<<dim3(64, 4, 4), blk, 0, stream>>>(
            attb, 1024, M8, M1, vbuf, 1024, M8, M1,
            ot, 1024, M8, M1, 1024,
            nullptr, 0, gamma, xtq, 1024);
        // attb dead: cast FC weights into its region (re-done each pass)
        cast_f2b<<<512, blk, 0, stream>>>(W1, W1b, 128 * 1024);
        cast_f2b<<<64, blk, 0, stream>>>(W2, W2b, 128 * 128);
        // fc1+fc2 fused (ring): M=32768 rows, 256 blocks of 128 rows
        fc_fused<<<dim3(1, 256, 1), blk, 0, stream>>>(
            ot, W1b, W2b, b1, b2, out + b0 * M1, x + b0 * M1);
    }
}